// Round 10
// baseline (163.545 us; speedup 1.0000x reference)
//
#include <hip/hip_runtime.h>
#include <hip/hip_bf16.h>

typedef float f32x4 __attribute__((ext_vector_type(4)));
typedef __bf16 bf16x8 __attribute__((ext_vector_type(8)));
typedef unsigned short u16x8 __attribute__((ext_vector_type(8)));

#define N_NODES 10000
#define DIM 512
#define MPAD 10112   // 158 * 64
#define DEGCAP 96    // max degree bucket (Poisson(15): P(deg>=96) ~ 1e-40)

// ============ ATTRIBUTION ROUND: gather x4, gemm x4, LN x16 (in-kernel) ========
// Each amplified kernel exceeds the ~40us harness-fill threshold so it appears
// in top-5 BY NAME with its own counters. Results are exact up to ulp jitter
// (scales 1/4 and 1/16 are powers of two; rep loops re-accumulate then rescale).

// ---------------- zero cnt ------------------------------------------------------
__global__ __launch_bounds__(256) void zero_kernel(int* __restrict__ cnt) {
    cnt[blockIdx.x * 256 + threadIdx.x] = 0;
}

// ====== phase1: packw | layernorm(x16) | bucket-fill (grid-partitioned) ========
__global__ __launch_bounds__(256) void phase1_kernel(
    const float* __restrict__ wl, const float* __restrict__ wr,
    __hip_bfloat16* __restrict__ W,
    const float* __restrict__ xin, const float* __restrict__ gamma,
    const float* __restrict__ beta, __hip_bfloat16* __restrict__ A,
    const int* __restrict__ eidx, int* __restrict__ cnt, int* __restrict__ adj,
    int E, int fill_start) {
    int b = blockIdx.x;
    int tid = threadIdx.x;

    if (b < 512) {
        // pack W = [w_l | w_r] rows -> bf16 [512][1024]
        int idx = b * 256 + tid;
        int base = idx * 4;
        int d = base >> 10;
        int k = base & 1023;
        const float* src = (k < 512) ? (wl + d * 512 + k) : (wr + d * 512 + (k - 512));
        float4 v = *(const float4*)src;
        __hip_bfloat16* o = W + (size_t)d * 1024 + k;
        o[0] = __float2bfloat16(v.x);
        o[1] = __float2bfloat16(v.y);
        o[2] = __float2bfloat16(v.z);
        o[3] = __float2bfloat16(v.w);
    } else if (b < fill_start) {
        // LayerNorm, one wave per row  — x16 amplification (idempotent rewrite)
        for (int rep = 0; rep < 16; ++rep) {
            int row = (b - 512) * 4 + (tid >> 6);
            int lane = tid & 63;
            const float* xr = xin + (size_t)row * DIM + lane * 8;
            float4 v0 = *(const float4*)xr;
            float4 v1 = *(const float4*)(xr + 4);
            float s  = v0.x + v0.y + v0.z + v0.w + v1.x + v1.y + v1.z + v1.w;
            float ss = v0.x*v0.x + v0.y*v0.y + v0.z*v0.z + v0.w*v0.w
                     + v1.x*v1.x + v1.y*v1.y + v1.z*v1.z + v1.w*v1.w;
            #pragma unroll
            for (int o = 32; o > 0; o >>= 1) {
                s  += __shfl_xor(s, o, 64);
                ss += __shfl_xor(ss, o, 64);
            }
            float mu  = s * (1.0f / 512.0f);
            float var = ss * (1.0f / 512.0f) - mu * mu;
            float rstd = rsqrtf(var + 1e-5f);
            float4 g0 = *(const float4*)(gamma + lane * 8);
            float4 g1 = *(const float4*)(gamma + lane * 8 + 4);
            float4 b0 = *(const float4*)(beta + lane * 8);
            float4 b1 = *(const float4*)(beta + lane * 8 + 4);
            __hip_bfloat16* a = A + (size_t)row * 1024 + 512 + lane * 8;
            a[0] = __float2bfloat16((v0.x - mu) * rstd * g0.x + b0.x);
            a[1] = __float2bfloat16((v0.y - mu) * rstd * g0.y + b0.y);
            a[2] = __float2bfloat16((v0.z - mu) * rstd * g0.z + b0.z);
            a[3] = __float2bfloat16((v0.w - mu) * rstd * g0.w + b0.w);
            a[4] = __float2bfloat16((v1.x - mu) * rstd * g1.x + b1.x);
            a[5] = __float2bfloat16((v1.y - mu) * rstd * g1.y + b1.y);
            a[6] = __float2bfloat16((v1.z - mu) * rstd * g1.z + b1.z);
            a[7] = __float2bfloat16((v1.w - mu) * rstd * g1.w + b1.w);
            asm volatile("" ::: "memory");
        }
    } else {
        // single-pass bucket fill: adj[dst*DEGCAP + pos] = src  (x1 — atomics)
        int i = (b - fill_start) * 256 + tid;
        if (i < E) {
            int dst = eidx[E + i];
            int src = eidx[i];
            int pos = atomicAdd(&cnt[dst], 1);
            if (pos < DEGCAP) adj[dst * DEGCAP + pos] = src;
        }
    }
}

// ---------------- gather: wave/node, 8-deep MLP unroll — x4 amplification ------
__global__ __launch_bounds__(256) void gather_kernel(const int* __restrict__ cnt,
                                                     const int* __restrict__ adj,
                                                     __hip_bfloat16* __restrict__ A) {
    int gw = (blockIdx.x * 256 + threadIdx.x) >> 6;
    int lane = threadIdx.x & 63;
    int deg = cnt[gw];
    const int* al = adj + gw * DEGCAP;
    float acc0[8] = {}, acc1[8] = {};
    for (int rep = 0; rep < 4; ++rep) {
        int j = 0;
        for (; j + 8 <= deg; j += 8) {
            int a0 = al[j], a1 = al[j+1], a2 = al[j+2], a3 = al[j+3];
            int a4 = al[j+4], a5 = al[j+5], a6 = al[j+6], a7 = al[j+7];
            u16x8 v0 = *(const u16x8*)(A + (size_t)a0 * 1024 + 512 + lane * 8);
            u16x8 v1 = *(const u16x8*)(A + (size_t)a1 * 1024 + 512 + lane * 8);
            u16x8 v2 = *(const u16x8*)(A + (size_t)a2 * 1024 + 512 + lane * 8);
            u16x8 v3 = *(const u16x8*)(A + (size_t)a3 * 1024 + 512 + lane * 8);
            u16x8 v4 = *(const u16x8*)(A + (size_t)a4 * 1024 + 512 + lane * 8);
            u16x8 v5 = *(const u16x8*)(A + (size_t)a5 * 1024 + 512 + lane * 8);
            u16x8 v6 = *(const u16x8*)(A + (size_t)a6 * 1024 + 512 + lane * 8);
            u16x8 v7 = *(const u16x8*)(A + (size_t)a7 * 1024 + 512 + lane * 8);
            #pragma unroll
            for (int k = 0; k < 8; ++k) {
                acc0[k] += __uint_as_float((unsigned)v0[k] << 16)
                         + __uint_as_float((unsigned)v1[k] << 16)
                         + __uint_as_float((unsigned)v2[k] << 16)
                         + __uint_as_float((unsigned)v3[k] << 16);
                acc1[k] += __uint_as_float((unsigned)v4[k] << 16)
                         + __uint_as_float((unsigned)v5[k] << 16)
                         + __uint_as_float((unsigned)v6[k] << 16)
                         + __uint_as_float((unsigned)v7[k] << 16);
            }
        }
        for (; j + 4 <= deg; j += 4) {
            int a0 = al[j], a1 = al[j+1], a2 = al[j+2], a3 = al[j+3];
            u16x8 v0 = *(const u16x8*)(A + (size_t)a0 * 1024 + 512 + lane * 8);
            u16x8 v1 = *(const u16x8*)(A + (size_t)a1 * 1024 + 512 + lane * 8);
            u16x8 v2 = *(const u16x8*)(A + (size_t)a2 * 1024 + 512 + lane * 8);
            u16x8 v3 = *(const u16x8*)(A + (size_t)a3 * 1024 + 512 + lane * 8);
            #pragma unroll
            for (int k = 0; k < 8; ++k) {
                acc0[k] += __uint_as_float((unsigned)v0[k] << 16)
                         + __uint_as_float((unsigned)v1[k] << 16);
                acc1[k] += __uint_as_float((unsigned)v2[k] << 16)
                         + __uint_as_float((unsigned)v3[k] << 16);
            }
        }
        for (; j < deg; ++j) {
            int a0 = al[j];
            u16x8 v0 = *(const u16x8*)(A + (size_t)a0 * 1024 + 512 + lane * 8);
            #pragma unroll
            for (int k = 0; k < 8; ++k)
                acc0[k] += __uint_as_float((unsigned)v0[k] << 16);
        }
        asm volatile("" ::: "memory");
    }
    float sc = 0.25f / fmaxf((float)deg, 1.0f);   // 1/4 rep correction (exact)
    __hip_bfloat16* o = A + (size_t)gw * 1024 + lane * 8;
    #pragma unroll
    for (int k = 0; k < 8; ++k)
        o[k] = __float2bfloat16((acc0[k] + acc1[k]) * sc);
}

// ---------------- GEMM x4: 128 flattened K-steps, acc*0.25 --------------------
__global__ __launch_bounds__(256) void gemm_kernel(const __hip_bfloat16* __restrict__ A,
                                                   const __hip_bfloat16* __restrict__ Wb,
                                                   const float* __restrict__ bias,
                                                   const float* __restrict__ resid,
                                                   float* __restrict__ out) {
    __shared__ __hip_bfloat16 As[3][64 * 32];
    __shared__ __hip_bfloat16 Bs[3][64 * 32];
    const int tid = threadIdx.x;
    const int lane = tid & 63;
    const int w = tid >> 6;
    const int wr = w >> 1, wc = w & 1;   // 2x2 waves, wave tile 32x32

    int bid = blockIdx.x;
    int tl = (bid & 7) * 158 + (bid >> 3);   // XCD-chunked bijective swizzle
    int mx = tl >> 3, ny = tl & 7;
    const size_t arow0 = (size_t)mx * 64;
    const size_t bcol0 = (size_t)ny * 64;

    f32x4 acc[2][2] = {};

    const int rsw = ((lane & 15) >> 1) & 3;
    const int csw = (((lane >> 4) ^ rsw) & 3) * 8;

#define STAGE(buf, t)                                                                \
    {                                                                                \
        int r = tid >> 2, sl = tid & 3;                                              \
        int c8 = sl ^ ((r >> 1) & 3);                                                \
        const __hip_bfloat16* ga = A + (size_t)(arow0 + r) * 1024 + (t) * 32 + c8 * 8; \
        __builtin_amdgcn_global_load_lds(                                            \
            (const __attribute__((address_space(1))) void*)ga,                       \
            (__attribute__((address_space(3))) void*)(As[buf] + tid * 8), 16, 0, 0); \
        const __hip_bfloat16* gb = Wb + (size_t)(bcol0 + r) * 1024 + (t) * 32 + c8 * 8; \
        __builtin_amdgcn_global_load_lds(                                            \
            (const __attribute__((address_space(1))) void*)gb,                       \
            (__attribute__((address_space(3))) void*)(Bs[buf] + tid * 8), 16, 0, 0); \
    }

    STAGE(0, 0)
    STAGE(1, 1)

    for (int step = 0; step < 128; ++step) {
        if (step < 126) { asm volatile("s_waitcnt vmcnt(2)" ::: "memory"); }
        else            { asm volatile("s_waitcnt vmcnt(0)" ::: "memory"); }
        __builtin_amdgcn_s_barrier();
        __builtin_amdgcn_sched_barrier(0);
        if (step + 2 < 128) STAGE((step + 2) % 3, (step + 2) & 31)

        const int p = step % 3;
        const int t = step & 31;
        (void)t;
        bf16x8 af[2], bfr[2];
        #pragma unroll
        for (int m = 0; m < 2; ++m)
            af[m] = *(const bf16x8*)(As[p] + (wr * 32 + m * 16 + (lane & 15)) * 32 + csw);
        #pragma unroll
        for (int n = 0; n < 2; ++n)
            bfr[n] = *(const bf16x8*)(Bs[p] + (wc * 32 + n * 16 + (lane & 15)) * 32 + csw);
        #pragma unroll
        for (int m = 0; m < 2; ++m)
            #pragma unroll
            for (int n = 0; n < 2; ++n)
                acc[m][n] = __builtin_amdgcn_mfma_f32_16x16x32_bf16(af[m], bfr[n], acc[m][n], 0, 0, 0);
    }
#undef STAGE

    #pragma unroll
    for (int m = 0; m < 2; ++m) {
        int rowb = (int)arow0 + wr * 32 + m * 16 + (lane >> 4) * 4;
        #pragma unroll
        for (int n = 0; n < 2; ++n) {
            int col = (int)bcol0 + wc * 32 + n * 16 + (lane & 15);
            float bv = bias[col];
            #pragma unroll
            for (int j = 0; j < 4; ++j) {
                int row = rowb + j;
                if (row < N_NODES) {
                    float v = acc[m][n][j] * 0.25f + bv;   // 1/4 rep correction
                    v = v > 0.0f ? v : 0.0f;
                    out[(size_t)row * 512 + col] = v + resid[(size_t)row * 512 + col];
                }
            }
        }
    }
}

extern "C" void kernel_launch(void* const* d_in, const int* in_sizes, int n_in,
                              void* d_out, int out_size, void* d_ws, size_t ws_size,
                              hipStream_t stream) {
    const float* node  = (const float*)d_in[0];
    const int*   eidx  = (const int*)d_in[1];
    const float* gamma = (const float*)d_in[2];
    const float* beta  = (const float*)d_in[3];
    const float* wl    = (const float*)d_in[4];
    const float* bl    = (const float*)d_in[5];
    const float* wr    = (const float*)d_in[6];
    float* out = (float*)d_out;
    const int E = in_sizes[1] / 2;

    char* ws = (char*)d_ws;
    int* cnt = (int*)ws;                                   // [10240]
    int* adj = cnt + 10240;                                // [N_NODES * DEGCAP]
    size_t adj_bytes = ((size_t)N_NODES * DEGCAP * 4 + 255) & ~(size_t)255;
    __hip_bfloat16* A = (__hip_bfloat16*)((char*)adj + adj_bytes);
    __hip_bfloat16* W = (__hip_bfloat16*)((char*)A + (size_t)MPAD * 1024 * 2);

    const int fill_start = 512 + 2500;
    const int nFill = (E + 255) / 256;

    zero_kernel<<<40, 256, 0, stream>>>(cnt);
    phase1_kernel<<<fill_start + nFill, 256, 0, stream>>>(
        wl, wr, W, node, gamma, beta, A, eidx, cnt, adj, E, fill_start);
    gather_kernel<<<(N_NODES * 64) / 256, 256, 0, stream>>>(cnt, adj, A);
    gemm_kernel<<<1264, 256, 0, stream>>>(A, W, bl, node, out);
}

// Round 11
// 72.187 us; speedup vs baseline: 2.2656x; 2.2656x over previous
//
#include <hip/hip_runtime.h>
#include <hip/hip_bf16.h>

typedef float f32x4 __attribute__((ext_vector_type(4)));
typedef __bf16 bf16x8 __attribute__((ext_vector_type(8)));
typedef unsigned short u16x8 __attribute__((ext_vector_type(8)));

#define N_NODES 10000
#define DIM 512
#define MPAD 10112   // 158 * 64
#define DEGCAP 96    // max degree bucket (Poisson(15): P(deg>=96) ~ 1e-40)

// ---------------- zero cnt ------------------------------------------------------
__global__ __launch_bounds__(256) void zero_kernel(int* __restrict__ cnt) {
    cnt[blockIdx.x * 256 + threadIdx.x] = 0;
}

// ====== phase1: packw | layernorm | bucket-fill adjacency (FROZEN, R9) =========
__global__ __launch_bounds__(256) void phase1_kernel(
    const float* __restrict__ wl, const float* __restrict__ wr,
    __hip_bfloat16* __restrict__ W,
    const float* __restrict__ xin, const float* __restrict__ gamma,
    const float* __restrict__ beta, __hip_bfloat16* __restrict__ A,
    const int* __restrict__ eidx, int* __restrict__ cnt, int* __restrict__ adj,
    int E, int fill_start) {
    int b = blockIdx.x;
    int tid = threadIdx.x;

    if (b < 512) {
        int idx = b * 256 + tid;
        int base = idx * 4;
        int d = base >> 10;
        int k = base & 1023;
        const float* src = (k < 512) ? (wl + d * 512 + k) : (wr + d * 512 + (k - 512));
        float4 v = *(const float4*)src;
        __hip_bfloat16* o = W + (size_t)d * 1024 + k;
        o[0] = __float2bfloat16(v.x);
        o[1] = __float2bfloat16(v.y);
        o[2] = __float2bfloat16(v.z);
        o[3] = __float2bfloat16(v.w);
    } else if (b < fill_start) {
        int row = (b - 512) * 4 + (tid >> 6);
        int lane = tid & 63;
        const float* xr = xin + (size_t)row * DIM + lane * 8;
        float4 v0 = *(const float4*)xr;
        float4 v1 = *(const float4*)(xr + 4);
        float s  = v0.x + v0.y + v0.z + v0.w + v1.x + v1.y + v1.z + v1.w;
        float ss = v0.x*v0.x + v0.y*v0.y + v0.z*v0.z + v0.w*v0.w
                 + v1.x*v1.x + v1.y*v1.y + v1.z*v1.z + v1.w*v1.w;
        #pragma unroll
        for (int o = 32; o > 0; o >>= 1) {
            s  += __shfl_xor(s, o, 64);
            ss += __shfl_xor(ss, o, 64);
        }
        float mu  = s * (1.0f / 512.0f);
        float var = ss * (1.0f / 512.0f) - mu * mu;
        float rstd = rsqrtf(var + 1e-5f);
        float4 g0 = *(const float4*)(gamma + lane * 8);
        float4 g1 = *(const float4*)(gamma + lane * 8 + 4);
        float4 b0 = *(const float4*)(beta + lane * 8);
        float4 b1 = *(const float4*)(beta + lane * 8 + 4);
        __hip_bfloat16* a = A + (size_t)row * 1024 + 512 + lane * 8;
        a[0] = __float2bfloat16((v0.x - mu) * rstd * g0.x + b0.x);
        a[1] = __float2bfloat16((v0.y - mu) * rstd * g0.y + b0.y);
        a[2] = __float2bfloat16((v0.z - mu) * rstd * g0.z + b0.z);
        a[3] = __float2bfloat16((v0.w - mu) * rstd * g0.w + b0.w);
        a[4] = __float2bfloat16((v1.x - mu) * rstd * g1.x + b1.x);
        a[5] = __float2bfloat16((v1.y - mu) * rstd * g1.y + b1.y);
        a[6] = __float2bfloat16((v1.z - mu) * rstd * g1.z + b1.z);
        a[7] = __float2bfloat16((v1.w - mu) * rstd * g1.w + b1.w);
    } else {
        int i = (b - fill_start) * 256 + tid;
        if (i < E) {
            int dst = eidx[E + i];
            int src = eidx[i];
            int pos = atomicAdd(&cnt[dst], 1);
            if (pos < DEGCAP) adj[dst * DEGCAP + pos] = src;
        }
    }
}

// ---------------- gather: wave/node, 8-deep MLP unroll (FROZEN, R9) ------------
__global__ __launch_bounds__(256) void gather_kernel(const int* __restrict__ cnt,
                                                     const int* __restrict__ adj,
                                                     __hip_bfloat16* __restrict__ A) {
    int gw = (blockIdx.x * 256 + threadIdx.x) >> 6;
    int lane = threadIdx.x & 63;
    int deg = cnt[gw];
    const int* al = adj + gw * DEGCAP;
    float acc0[8] = {}, acc1[8] = {};
    int j = 0;
    for (; j + 8 <= deg; j += 8) {
        int a0 = al[j], a1 = al[j+1], a2 = al[j+2], a3 = al[j+3];
        int a4 = al[j+4], a5 = al[j+5], a6 = al[j+6], a7 = al[j+7];
        u16x8 v0 = *(const u16x8*)(A + (size_t)a0 * 1024 + 512 + lane * 8);
        u16x8 v1 = *(const u16x8*)(A + (size_t)a1 * 1024 + 512 + lane * 8);
        u16x8 v2 = *(const u16x8*)(A + (size_t)a2 * 1024 + 512 + lane * 8);
        u16x8 v3 = *(const u16x8*)(A + (size_t)a3 * 1024 + 512 + lane * 8);
        u16x8 v4 = *(const u16x8*)(A + (size_t)a4 * 1024 + 512 + lane * 8);
        u16x8 v5 = *(const u16x8*)(A + (size_t)a5 * 1024 + 512 + lane * 8);
        u16x8 v6 = *(const u16x8*)(A + (size_t)a6 * 1024 + 512 + lane * 8);
        u16x8 v7 = *(const u16x8*)(A + (size_t)a7 * 1024 + 512 + lane * 8);
        #pragma unroll
        for (int k = 0; k < 8; ++k) {
            acc0[k] += __uint_as_float((unsigned)v0[k] << 16)
                     + __uint_as_float((unsigned)v1[k] << 16)
                     + __uint_as_float((unsigned)v2[k] << 16)
                     + __uint_as_float((unsigned)v3[k] << 16);
            acc1[k] += __uint_as_float((unsigned)v4[k] << 16)
                     + __uint_as_float((unsigned)v5[k] << 16)
                     + __uint_as_float((unsigned)v6[k] << 16)
                     + __uint_as_float((unsigned)v7[k] << 16);
        }
    }
    for (; j + 4 <= deg; j += 4) {
        int a0 = al[j], a1 = al[j+1], a2 = al[j+2], a3 = al[j+3];
        u16x8 v0 = *(const u16x8*)(A + (size_t)a0 * 1024 + 512 + lane * 8);
        u16x8 v1 = *(const u16x8*)(A + (size_t)a1 * 1024 + 512 + lane * 8);
        u16x8 v2 = *(const u16x8*)(A + (size_t)a2 * 1024 + 512 + lane * 8);
        u16x8 v3 = *(const u16x8*)(A + (size_t)a3 * 1024 + 512 + lane * 8);
        #pragma unroll
        for (int k = 0; k < 8; ++k) {
            acc0[k] += __uint_as_float((unsigned)v0[k] << 16)
                     + __uint_as_float((unsigned)v1[k] << 16);
            acc1[k] += __uint_as_float((unsigned)v2[k] << 16)
                     + __uint_as_float((unsigned)v3[k] << 16);
        }
    }
    for (; j < deg; ++j) {
        int a0 = al[j];
        u16x8 v0 = *(const u16x8*)(A + (size_t)a0 * 1024 + 512 + lane * 8);
        #pragma unroll
        for (int k = 0; k < 8; ++k)
            acc0[k] += __uint_as_float((unsigned)v0[k] << 16);
    }
    float sc = 1.0f / fmaxf((float)deg, 1.0f);
    __hip_bfloat16* o = A + (size_t)gw * 1024 + lane * 8;
    #pragma unroll
    for (int k = 0; k < 8; ++k)
        o[k] = __float2bfloat16((acc0[k] + acc1[k]) * sc);
}

// ---------------- GEMM: wave-split-K, ZERO main-loop barriers ------------------
// BM=64, BN=64. Each of 4 waves owns K-chunk of 256 (8 sub-tiles of BK=32) with
// a PRIVATE 16KB double-buffered LDS region. vmcnt is per-wave; in-order
// completion means vmcnt(8) == "my previous tile landed". No cross-wave LDS
// sharing until the final reduction barrier -> race-free by construction.
__global__ __launch_bounds__(256) void gemm_kernel(const __hip_bfloat16* __restrict__ A,
                                                   const __hip_bfloat16* __restrict__ Wb,
                                                   const float* __restrict__ bias,
                                                   const float* __restrict__ resid,
                                                   float* __restrict__ out) {
    __shared__ __hip_bfloat16 lds[4][8192];   // 64 KB: per-wave [A0|B0|A1|B1] x 2048 elems
    const int tid = threadIdx.x;
    const int lane = tid & 63;
    const int w = tid >> 6;

    int bid = blockIdx.x;
    int tl = (bid & 7) * 158 + (bid >> 3);   // XCD-chunked bijective swizzle
    int mx = tl >> 3, ny = tl & 7;           // 8 consecutive tl share the A-panel
    const size_t arow0 = (size_t)mx * 64;
    const size_t bcol0 = (size_t)ny * 64;

    __hip_bfloat16* Aw0 = &lds[w][0];
    __hip_bfloat16* Bw0 = &lds[w][2048];
    __hip_bfloat16* Aw1 = &lds[w][4096];
    __hip_bfloat16* Bw1 = &lds[w][6144];
    const int kw0 = w * 256;                 // this wave's K-chunk

    f32x4 acc[4][4] = {};

    const int rsw = ((lane & 15) >> 1) & 3;
    const int csw = (((lane >> 4) ^ rsw) & 3) * 8;
    const int srr = lane >> 2;               // staging row within 16-row group
    const int scc = lane & 3;                // staging chunk slot

    // 8 global_load_lds per STAGE (4 A + 4 B), swizzled source, linear LDS dest
#define STAGE(bufA, bufB, kb)                                                          \
    {                                                                                  \
        _Pragma("unroll")                                                              \
        for (int it = 0; it < 4; ++it) {                                               \
            int rr = it * 16 + srr;                                                    \
            int c8 = scc ^ ((rr >> 1) & 3);                                            \
            const __hip_bfloat16* ga = A + (size_t)(arow0 + rr) * 1024 + (kb) + c8 * 8; \
            __builtin_amdgcn_global_load_lds(                                          \
                (const __attribute__((address_space(1))) void*)ga,                     \
                (__attribute__((address_space(3))) void*)((bufA) + it * 512 + lane * 8), 16, 0, 0); \
        }                                                                              \
        _Pragma("unroll")                                                              \
        for (int it = 0; it < 4; ++it) {                                               \
            int rr = it * 16 + srr;                                                    \
            int c8 = scc ^ ((rr >> 1) & 3);                                            \
            const __hip_bfloat16* gb = Wb + (size_t)(bcol0 + rr) * 1024 + (kb) + c8 * 8; \
            __builtin_amdgcn_global_load_lds(                                          \
                (const __attribute__((address_space(1))) void*)gb,                     \
                (__attribute__((address_space(3))) void*)((bufB) + it * 512 + lane * 8), 16, 0, 0); \
        }                                                                              \
    }

    STAGE(Aw0, Bw0, kw0)

    #pragma unroll 1
    for (int t = 0; t < 8; ++t) {
        const __hip_bfloat16* pa = (t & 1) ? Aw1 : Aw0;
        const __hip_bfloat16* pb = (t & 1) ? Bw1 : Bw0;
        if (t + 1 < 8) {
            __hip_bfloat16* na = (t & 1) ? Aw0 : Aw1;
            __hip_bfloat16* nb = (t & 1) ? Bw0 : Bw1;
            STAGE(na, nb, kw0 + (t + 1) * 32)
            asm volatile("s_waitcnt vmcnt(8)" ::: "memory");   // my tile-t landed
        } else {
            asm volatile("s_waitcnt vmcnt(0)" ::: "memory");
        }
        bf16x8 af[4], bfr[4];
        #pragma unroll
        for (int m = 0; m < 4; ++m)
            af[m] = *(const bf16x8*)(pa + (m * 16 + (lane & 15)) * 32 + csw);
        #pragma unroll
        for (int n = 0; n < 4; ++n)
            bfr[n] = *(const bf16x8*)(pb + (n * 16 + (lane & 15)) * 32 + csw);
        #pragma unroll
        for (int m = 0; m < 4; ++m)
            #pragma unroll
            for (int n = 0; n < 4; ++n)
                acc[m][n] = __builtin_amdgcn_mfma_f32_16x16x32_bf16(af[m], bfr[n], acc[m][n], 0, 0, 0);
    }
#undef STAGE

    // ---- reduction: 4 partial 64x64 f32 tiles through LDS ----
    float* red = (float*)&lds[0][0];         // 16384 f32 = 64 KB
    float* myred = red + w * 4096;
    const int coli = lane & 15;
    const int rowi0 = (lane >> 4) * 4;
    #pragma unroll
    for (int m = 0; m < 4; ++m)
        #pragma unroll
        for (int n = 0; n < 4; ++n)
            #pragma unroll
            for (int j = 0; j < 4; ++j)
                myred[(m * 16 + rowi0 + j) * 64 + n * 16 + coli] = acc[m][n][j];
    __syncthreads();

    #pragma unroll
    for (int g = 0; g < 4; ++g) {
        int e = g * 1024 + tid * 4;          // contiguous per-lane -> conflict-free
        int row = e >> 6;
        int col = e & 63;
        int grow = (int)arow0 + row;
        if (grow < N_NODES) {
            f32x4 s = *(const f32x4*)(red + e)
                    + *(const f32x4*)(red + 4096 + e)
                    + *(const f32x4*)(red + 8192 + e)
                    + *(const f32x4*)(red + 12288 + e);
            int gcol = (int)bcol0 + col;
            float4 bv = *(const float4*)(bias + gcol);
            float4 rv = *(const float4*)(resid + (size_t)grow * 512 + gcol);
            float4 o;
            o.x = fmaxf(s[0] + bv.x, 0.f) + rv.x;
            o.y = fmaxf(s[1] + bv.y, 0.f) + rv.y;
            o.z = fmaxf(s[2] + bv.z, 0.f) + rv.z;
            o.w = fmaxf(s[3] + bv.w, 0.f) + rv.w;
            *(float4*)(out + (size_t)grow * 512 + gcol) = o;
        }
    }
}

extern "C" void kernel_launch(void* const* d_in, const int* in_sizes, int n_in,
                              void* d_out, int out_size, void* d_ws, size_t ws_size,
                              hipStream_t stream) {
    const float* node  = (const float*)d_in[0];
    const int*   eidx  = (const int*)d_in[1];
    const float* gamma = (const float*)d_in[2];
    const float* beta  = (const float*)d_in[3];
    const float* wl    = (const float*)d_in[4];
    const float* bl    = (const float*)d_in[5];
    const float* wr    = (const float*)d_in[6];
    float* out = (float*)d_out;
    const int E = in_sizes[1] / 2;

    char* ws = (char*)d_ws;
    int* cnt = (int*)ws;                                   // [10240]
    int* adj = cnt + 10240;                                // [N_NODES * DEGCAP]
    size_t adj_bytes = ((size_t)N_NODES * DEGCAP * 4 + 255) & ~(size_t)255;
    __hip_bfloat16* A = (__hip_bfloat16*)((char*)adj + adj_bytes);
    __hip_bfloat16* W = (__hip_bfloat16*)((char*)A + (size_t)MPAD * 1024 * 2);

    const int fill_start = 512 + 2500;
    const int nFill = (E + 255) / 256;

    zero_kernel<<<40, 256, 0, stream>>>(cnt);
    phase1_kernel<<<fill_start + nFill, 256, 0, stream>>>(
        wl, wr, W, node, gamma, beta, A, eidx, cnt, adj, E, fill_start);
    gather_kernel<<<(N_NODES * 64) / 256, 256, 0, stream>>>(cnt, adj, A);
    gemm_kernel<<<1264, 256, 0, stream>>>(A, W, bl, node, out);
}